// Round 10
// baseline (2174.428 us; speedup 1.0000x reference)
//
#include <hip/hip_runtime.h>
#include <hip/hip_bf16.h>

// MEASUREMENT ROUND 2 (GEMM under the microscope):
//   K1: FPS (blocks 0-15) || W->bf16 packed (16-255)   [R9 exact, x1]
//   K2: KNN (512 blocks, 8 waves)                      [R9 exact, x1]
//   K3: gather-fused GEMM x GREP reps -> lands in rocprof top-5 WITH counters.
//       Improvements: [64][44] LDS pad (2-way-free banks), 4-buffer staging,
//       depth-4 prefetch, 2 barriers per 4 K-steps, launch_bounds(512,4).

#define NPTS 8192
#define SPTS 32
#define KNN_K 12
#define DS 256
#define DT 1024
#define DOUT 1024
#define GREP 32

typedef float f32x4 __attribute__((ext_vector_type(4)));
typedef __bf16 bf16x8 __attribute__((ext_vector_type(8)));
typedef unsigned short ushort_t;
typedef unsigned long long u64;

__device__ __forceinline__ ushort_t f2bf(float f) {
    unsigned int u = __float_as_uint(f);
    u += 0x7fffu + ((u >> 16) & 1u);   // RNE
    return (ushort_t)(u >> 16);
}

// ==================== K1: FPS || W convert (packed) ====================
// Packed layout: element (col,k) -> [k>>5]*(DOUT*32) + col*32 + (k&31)
__global__ __launch_bounds__(512) void fps_convw_kernel(const float* __restrict__ xyz,
                                                        float* __restrict__ new_xyz,
                                                        const float* __restrict__ Wt,
                                                        ushort_t* __restrict__ Wb_t,
                                                        const float* __restrict__ Ws,
                                                        ushort_t* __restrict__ Wb_s) {
    int bid = blockIdx.x;
    int tid = threadIdx.x;

    if (bid >= 16) {
        int lin = (bid - 16) * 512 + tid;
        const int stride = 240 * 512;
        for (int i = lin; i < (DT * DOUT) / 4; i += stride) {   // t: KD=1024
            int col = i >> 8, k4 = i & 255;
            float4 v = reinterpret_cast<const float4*>(Wt)[i];
            ushort4 u;
            u.x = f2bf(v.x); u.y = f2bf(v.y); u.z = f2bf(v.z); u.w = f2bf(v.w);
            size_t off = (size_t)(k4 >> 3) * (DOUT * 32) + col * 32 + (k4 & 7) * 4;
            *reinterpret_cast<ushort4*>(Wb_t + off) = u;
        }
        for (int i = lin; i < (DS * DOUT) / 4; i += stride) {   // s: KD=256
            int col = i >> 6, k4 = i & 63;
            float4 v = reinterpret_cast<const float4*>(Ws)[i];
            ushort4 u;
            u.x = f2bf(v.x); u.y = f2bf(v.y); u.z = f2bf(v.z); u.w = f2bf(v.w);
            size_t off = (size_t)(k4 >> 3) * (DOUT * 32) + col * 32 + (k4 & 7) * 4;
            *reinterpret_cast<ushort4*>(Wb_s + off) = u;
        }
        return;
    }

    {
#pragma clang fp contract(off)
        int b = bid;
        const float* base = xyz + (size_t)b * NPTS * 3;

        __shared__ float cx[NPTS], cy[NPTS], cz[NPTS];   // 96 KB coord table
        __shared__ u64 rkey[2][8];

        float px[16], py[16], pz[16], dd[16];
#pragma unroll
        for (int i = 0; i < 16; ++i) {
            int p = tid + i * 512;
            px[i] = base[p * 3 + 0];
            py[i] = base[p * 3 + 1];
            pz[i] = base[p * 3 + 2];
            dd[i] = 1e10f;
            cx[p] = px[i]; cy[p] = py[i]; cz[p] = pz[i];
        }

        float lx = base[0], ly = base[1], lz = base[2];
        if (tid == 0) {
            new_xyz[((size_t)b * SPTS + 0) * 3 + 0] = lx;
            new_xyz[((size_t)b * SPTS + 0) * 3 + 1] = ly;
            new_xyz[((size_t)b * SPTS + 0) * 3 + 2] = lz;
        }

        int w = tid >> 6;
        for (int it = 1; it < SPTS; ++it) {
            int par = it & 1;
            u64 bk = 0;
#pragma unroll
            for (int i = 0; i < 16; ++i) {
                float dx = px[i] - lx, dy = py[i] - ly, dz = pz[i] - lz;
                float d = dx * dx + dy * dy;
                d = d + dz * dz;
                float nd = fminf(dd[i], d);
                dd[i] = nd;
                u64 kd = ((u64)__float_as_uint(nd) << 32) | (unsigned)(8191 - (tid + i * 512));
                bk = (kd > bk) ? kd : bk;
            }
#pragma unroll
            for (int off = 1; off < 64; off <<= 1) {
                u64 ok = __shfl_xor(bk, off);
                bk = (ok > bk) ? ok : bk;
            }
            if ((tid & 63) == 0) rkey[par][w] = bk;
            __syncthreads();
            u64 nk = rkey[par][0];
#pragma unroll
            for (int w2 = 1; w2 < 8; ++w2) {
                u64 v2 = rkey[par][w2];
                nk = (v2 > nk) ? v2 : nk;
            }
            int idx = 8191 - (int)(unsigned)(nk & 0xFFFFFFFFull);
            lx = cx[idx]; ly = cy[idx]; lz = cz[idx];
            if (tid == 0) {
                new_xyz[((size_t)b * SPTS + it) * 3 + 0] = lx;
                new_xyz[((size_t)b * SPTS + it) * 3 + 1] = ly;
                new_xyz[((size_t)b * SPTS + it) * 3 + 2] = lz;
            }
        }
    }
}

// ==================== K2: KNN (R9 exact) ====================
__global__ __launch_bounds__(512) void knn_kernel(const float* __restrict__ xyz_s,
                                                  const float* __restrict__ xyz_t,
                                                  const float* __restrict__ new_xyz,
                                                  int* __restrict__ idx_s,
                                                  int* __restrict__ idx_t) {
#pragma clang fp contract(off)
    int q = blockIdx.x;
    int tid = threadIdx.x;
    int w = tid >> 6, lane = tid & 63;
    int set = w >> 2;
    int sw = w & 3;
    int b = q >> 5;

    const float* pts = (set ? xyz_t : xyz_s) + (size_t)b * NPTS * 3;

    float qx = new_xyz[q * 3 + 0];
    float qy = new_xyz[q * 3 + 1];
    float qz = new_xyz[q * 3 + 2];
    float qq = qx * qx + qy * qy;
    qq = qq + qz * qz;

    u64 bd[12];
#pragma unroll
    for (int j = 0; j < 12; ++j) bd[j] = ~0ULL;

    for (int i = 0; i < 2048 / 64; ++i) {
        int p = sw * 2048 + i * 64 + lane;
        float p0 = pts[p * 3 + 0], p1 = pts[p * 3 + 1], p2 = pts[p * 3 + 2];
        float pp = p0 * p0 + p1 * p1; pp = pp + p2 * p2;
        float dot = qx * p0 + qy * p1; dot = dot + qz * p2;
        float d = (qq - 2.0f * dot) + pp;
        unsigned u = __float_as_uint(d);
        u = (u & 0x80000000u) ? ~u : (u | 0x80000000u);
        u64 key = ((u64)u << 32) | (unsigned)p;
        if (key < bd[11]) {
#pragma unroll
            for (int j = 11; j > 0; --j) {
                bool keep = (key >= bd[j]);
                u64 sh = (key >= bd[j - 1]) ? key : bd[j - 1];
                bd[j] = keep ? bd[j] : sh;
            }
            if (key < bd[0]) bd[0] = key;
        }
    }

    __shared__ u64 sd[2][48];

#pragma unroll
    for (int r = 0; r < KNN_K; ++r) {
        u64 cv = bd[0];
#pragma unroll
        for (int off = 1; off < 64; off <<= 1) {
            u64 ov = __shfl_xor(cv, off);
            cv = (ov < cv) ? ov : cv;
        }
        if (lane == 0) sd[set][sw * KNN_K + r] = cv;
        if (cv == bd[0]) {
#pragma unroll
            for (int j = 0; j < 11; ++j) bd[j] = bd[j + 1];
            bd[11] = ~0ULL;
        }
    }
    __syncthreads();

    if (sw == 0) {
        int* outp = (set ? idx_t : idx_s) + q * KNN_K;
        u64 cd = (lane < 48) ? sd[set][lane] : ~0ULL;
#pragma unroll
        for (int r = 0; r < KNN_K; ++r) {
            u64 mv = cd;
#pragma unroll
            for (int off = 1; off < 64; off <<= 1) {
                u64 ov = __shfl_xor(mv, off);
                mv = (ov < mv) ? ov : mv;
            }
            if (lane == 0) outp[r] = (int)(unsigned)(mv & 0xFFFFFFFFull);
            if (cd == mv) cd = ~0ULL;
        }
    }
}

// ==================== K3: gather-fused GEMM (instrumented x GREP) ====================
// 512 blocks: t = bid<256 (4 queries x 512-col half, NK=32), s otherwise (NK=8).
// 4 LDS slabs [64][44] (stride 22 dwords: 2-way-free banks), depth-4 prefetch,
// 2 barriers per 4 K-steps. acc 4x4; MFMA k-order per acc identical to R9.
template <int KD>
__device__ __forceinline__ void gemm_body(int mblk, int ch, const float* __restrict__ feat,
                                          const int* __restrict__ idx,
                                          const ushort_t* __restrict__ Wb,
                                          const float* __restrict__ bias,
                                          const float* __restrict__ gamma,
                                          const float* __restrict__ beta,
                                          const float* __restrict__ mean,
                                          const float* __restrict__ var,
                                          float* __restrict__ out,
                                          ushort_t (*abuf)[64][44]) {
    const int NK = KD / 32;
    int tid = threadIdx.x;
    int w = tid >> 6, lane = tid & 63;
    int lrow = lane & 15, kgrp = lane >> 4;

    int r = tid >> 3, seg = tid & 7;
    int q = mblk * 4 + (r >> 4);
    int k = r & 15;
    bool valid = (k < KNN_K);
    int b = q >> 5;
    int src = valid ? idx[q * KNN_K + k] : 0;
    const float* srcp = feat + ((size_t)b * NPTS + src) * KD + seg * 4;

    f32x4 acc[4][4];
#pragma unroll
    for (int mi = 0; mi < 4; ++mi)
#pragma unroll
        for (int ni = 0; ni < 4; ++ni) {
            f32x4 z = {0.f, 0.f, 0.f, 0.f};
            acc[mi][ni] = z;
        }

    // prologue: stage slabs 0..3
#pragma unroll
    for (int j = 0; j < 4; ++j) {
        float4 v = {0.f, 0.f, 0.f, 0.f};
        if (valid && j < NK) v = *reinterpret_cast<const float4*>(srcp + j * 32);
        ushort4 u;
        u.x = f2bf(v.x); u.y = f2bf(v.y); u.z = f2bf(v.z); u.w = f2bf(v.w);
        *reinterpret_cast<ushort4*>(&abuf[j][r][seg * 4]) = u;
    }
    __syncthreads();

    for (int kk = 0; kk < NK; kk += 4) {
        // depth-4 prefetch: slabs kk+4 .. kk+7
        float4 nv0 = {0.f, 0.f, 0.f, 0.f}, nv1 = nv0, nv2 = nv0, nv3 = nv0;
        if (valid && kk + 4 < NK) {
            nv0 = *reinterpret_cast<const float4*>(srcp + (kk + 4) * 32);
            nv1 = *reinterpret_cast<const float4*>(srcp + (kk + 5) * 32);
            nv2 = *reinterpret_cast<const float4*>(srcp + (kk + 6) * 32);
            nv3 = *reinterpret_cast<const float4*>(srcp + (kk + 7) * 32);
        }

        // compute 4 sub-steps from slabs 0..3
#pragma unroll
        for (int ss = 0; ss < 4; ++ss) {
            bf16x8 a[4];
#pragma unroll
            for (int mf = 0; mf < 4; ++mf)
                a[mf] = *reinterpret_cast<const bf16x8*>(&abuf[ss][mf * 16 + lrow][kgrp * 8]);
#pragma unroll
            for (int nf = 0; nf < 4; ++nf) {
                int col = ch * 512 + w * 64 + nf * 16 + lrow;
                const ushort_t* bp = Wb + (size_t)(kk + ss) * (DOUT * 32) + (size_t)col * 32 + kgrp * 8;
                bf16x8 bfr = *reinterpret_cast<const bf16x8*>(bp);
#pragma unroll
                for (int mf = 0; mf < 4; ++mf)
                    acc[mf][nf] = __builtin_amdgcn_mfma_f32_16x16x32_bf16(a[mf], bfr, acc[mf][nf], 0, 0, 0);
            }
        }
        __syncthreads();   // all reads of abuf done

        if (kk + 4 < NK) {
            ushort4 u0, u1, u2, u3;
            u0.x = f2bf(nv0.x); u0.y = f2bf(nv0.y); u0.z = f2bf(nv0.z); u0.w = f2bf(nv0.w);
            u1.x = f2bf(nv1.x); u1.y = f2bf(nv1.y); u1.z = f2bf(nv1.z); u1.w = f2bf(nv1.w);
            u2.x = f2bf(nv2.x); u2.y = f2bf(nv2.y); u2.z = f2bf(nv2.z); u2.w = f2bf(nv2.w);
            u3.x = f2bf(nv3.x); u3.y = f2bf(nv3.y); u3.z = f2bf(nv3.z); u3.w = f2bf(nv3.w);
            *reinterpret_cast<ushort4*>(&abuf[0][r][seg * 4]) = u0;
            *reinterpret_cast<ushort4*>(&abuf[1][r][seg * 4]) = u1;
            *reinterpret_cast<ushort4*>(&abuf[2][r][seg * 4]) = u2;
            *reinterpret_cast<ushort4*>(&abuf[3][r][seg * 4]) = u3;
            __syncthreads();   // writes visible before next compute
        }
    }

    // epilogue: BN + ReLU + max over rows 0..11
#pragma unroll
    for (int nf = 0; nf < 4; ++nf) {
        int col = ch * 512 + w * 64 + nf * 16 + lrow;
        float sc = gamma[col] / sqrtf(var[col] + 1e-5f);
        float sh = (bias[col] - mean[col]) * sc + beta[col];
#pragma unroll
        for (int mf = 0; mf < 4; ++mf) {
            float m;
            if (kgrp < 3) {
                float y0 = fmaxf(acc[mf][nf][0] * sc + sh, 0.0f);
                float y1 = fmaxf(acc[mf][nf][1] * sc + sh, 0.0f);
                float y2 = fmaxf(acc[mf][nf][2] * sc + sh, 0.0f);
                float y3 = fmaxf(acc[mf][nf][3] * sc + sh, 0.0f);
                m = fmaxf(fmaxf(y0, y1), fmaxf(y2, y3));
            } else {
                m = -1e30f;
            }
            m = fmaxf(m, __shfl_xor(m, 16));
            m = fmaxf(m, __shfl_xor(m, 32));
            if (kgrp == 0) out[(size_t)(mblk * 4 + mf) * DOUT + col] = m;
        }
    }
}

struct GP {
    const float* feature_s; const float* feature_t;
    const int* idx_s; const int* idx_t;
    const ushort_t* Wb_s; const ushort_t* Wb_t;
    const float* bias_s; const float* gamma_s; const float* beta_s;
    const float* mean_s; const float* var_s;
    const float* bias_t; const float* gamma_t; const float* beta_t;
    const float* mean_t; const float* var_t;
    float* out;
};

__global__ __launch_bounds__(512, 4) void gemm_kernel(GP P) {
    __shared__ ushort_t abuf[4][64][44];   // 22.5 KB
    int bid = blockIdx.x;
    bool is_t = (bid < 256);
    int r2 = bid & 255;
    int mblk = r2 >> 1, ch = r2 & 1;
    for (int rep = 0; rep < GREP; ++rep) {
        if (is_t) {
            gemm_body<DT>(mblk, ch, P.feature_t, P.idx_t, P.Wb_t, P.bias_t, P.gamma_t,
                          P.beta_t, P.mean_t, P.var_t, P.out + (size_t)512 * 1024, abuf);
        } else {
            gemm_body<DS>(mblk, ch, P.feature_s, P.idx_s, P.Wb_s, P.bias_s, P.gamma_s,
                          P.beta_s, P.mean_s, P.var_s, P.out, abuf);
        }
        __syncthreads();   // protect abuf restage across reps
    }
}

extern "C" void kernel_launch(void* const* d_in, const int* in_sizes, int n_in,
                              void* d_out, int out_size, void* d_ws, size_t ws_size,
                              hipStream_t stream) {
    const float* feature_s = (const float*)d_in[0];
    const float* xyz_s     = (const float*)d_in[1];
    const float* feature_t = (const float*)d_in[2];
    const float* xyz_t     = (const float*)d_in[3];
    const float* Ws        = (const float*)d_in[4];
    const float* Wt        = (const float*)d_in[10];
    float* out = (float*)d_out;

    char* ws = (char*)d_ws;
    float* new_xyz  = (float*)(ws + 0);
    int* idx_s      = (int*)(ws + 8192);
    int* idx_t      = (int*)(ws + 32768);
    ushort_t* Wb_s  = (ushort_t*)(ws + 57344);
    ushort_t* Wb_t  = (ushort_t*)(ws + 581632);

    fps_convw_kernel<<<256, 512, 0, stream>>>(xyz_t, new_xyz, Wt, Wb_t, Ws, Wb_s);
    knn_kernel<<<512, 512, 0, stream>>>(xyz_s, xyz_t, new_xyz, idx_s, idx_t);

    GP P;
    P.feature_s = feature_s; P.feature_t = feature_t;
    P.idx_s = idx_s; P.idx_t = idx_t;
    P.Wb_s = Wb_s; P.Wb_t = Wb_t;
    P.bias_s = (const float*)d_in[5];  P.gamma_s = (const float*)d_in[6];
    P.beta_s = (const float*)d_in[7];  P.mean_s  = (const float*)d_in[8];
    P.var_s  = (const float*)d_in[9];
    P.bias_t = (const float*)d_in[11]; P.gamma_t = (const float*)d_in[12];
    P.beta_t = (const float*)d_in[13]; P.mean_t  = (const float*)d_in[14];
    P.var_t  = (const float*)d_in[15];
    P.out = out;

    gemm_kernel<<<512, 512, 0, stream>>>(P);
}

// Round 11
// 209.522 us; speedup vs baseline: 10.3781x; 10.3781x over previous
//
#include <hip/hip_runtime.h>
#include <hip/hip_bf16.h>

// RelationCos pipeline in 3 kernels:
//   K1: FPS (blocks 0-15, packed-u64 argmax + LDS coord table) || W->bf16 packed (16-255)
//   K2: KNN (512 blocks, 8 waves; packed-u64) -> idx in ws
//   K3: BARRIER-FREE gather GEMM: 1 wave = 1 query x 64 cols. A built in registers
//       (2x float4 + v_cvt_pk_bf16_f32), B dense 1KB wave-loads from packed W.
//       No LDS, no __syncthreads, 6 blocks/CU -> latency hidden by TLP.

#define NPTS 8192
#define SPTS 32
#define KNN_K 12
#define DS 256
#define DT 1024
#define DOUT 1024

typedef float f32x4 __attribute__((ext_vector_type(4)));
typedef __bf16 bf16x8 __attribute__((ext_vector_type(8)));
typedef unsigned short ushort_t;
typedef unsigned long long u64;

__device__ __forceinline__ ushort_t f2bf(float f) {
    unsigned int u = __float_as_uint(f);
    u += 0x7fffu + ((u >> 16) & 1u);   // RNE
    return (ushort_t)(u >> 16);
}

// ==================== K1: FPS || W convert (packed) ====================
// Packed layout: element (col,k) -> [k>>5]*(DOUT*32) + col*32 + (k&31)
__global__ __launch_bounds__(512) void fps_convw_kernel(const float* __restrict__ xyz,
                                                        float* __restrict__ new_xyz,
                                                        const float* __restrict__ Wt,
                                                        ushort_t* __restrict__ Wb_t,
                                                        const float* __restrict__ Ws,
                                                        ushort_t* __restrict__ Wb_s) {
    int bid = blockIdx.x;
    int tid = threadIdx.x;

    if (bid >= 16) {
        int lin = (bid - 16) * 512 + tid;
        const int stride = 240 * 512;
        for (int i = lin; i < (DT * DOUT) / 4; i += stride) {   // t: KD=1024
            int col = i >> 8, k4 = i & 255;
            float4 v = reinterpret_cast<const float4*>(Wt)[i];
            ushort4 u;
            u.x = f2bf(v.x); u.y = f2bf(v.y); u.z = f2bf(v.z); u.w = f2bf(v.w);
            size_t off = (size_t)(k4 >> 3) * (DOUT * 32) + col * 32 + (k4 & 7) * 4;
            *reinterpret_cast<ushort4*>(Wb_t + off) = u;
        }
        for (int i = lin; i < (DS * DOUT) / 4; i += stride) {   // s: KD=256
            int col = i >> 6, k4 = i & 63;
            float4 v = reinterpret_cast<const float4*>(Ws)[i];
            ushort4 u;
            u.x = f2bf(v.x); u.y = f2bf(v.y); u.z = f2bf(v.z); u.w = f2bf(v.w);
            size_t off = (size_t)(k4 >> 3) * (DOUT * 32) + col * 32 + (k4 & 7) * 4;
            *reinterpret_cast<ushort4*>(Wb_s + off) = u;
        }
        return;
    }

    {
#pragma clang fp contract(off)
        int b = bid;
        const float* base = xyz + (size_t)b * NPTS * 3;

        __shared__ float cx[NPTS], cy[NPTS], cz[NPTS];   // 96 KB coord table
        __shared__ u64 rkey[2][8];

        float px[16], py[16], pz[16], dd[16];
#pragma unroll
        for (int i = 0; i < 16; ++i) {
            int p = tid + i * 512;
            px[i] = base[p * 3 + 0];
            py[i] = base[p * 3 + 1];
            pz[i] = base[p * 3 + 2];
            dd[i] = 1e10f;
            cx[p] = px[i]; cy[p] = py[i]; cz[p] = pz[i];
        }

        float lx = base[0], ly = base[1], lz = base[2];
        if (tid == 0) {
            new_xyz[((size_t)b * SPTS + 0) * 3 + 0] = lx;
            new_xyz[((size_t)b * SPTS + 0) * 3 + 1] = ly;
            new_xyz[((size_t)b * SPTS + 0) * 3 + 2] = lz;
        }

        int w = tid >> 6;
        for (int it = 1; it < SPTS; ++it) {
            int par = it & 1;
            u64 bk = 0;
#pragma unroll
            for (int i = 0; i < 16; ++i) {
                float dx = px[i] - lx, dy = py[i] - ly, dz = pz[i] - lz;
                float d = dx * dx + dy * dy;
                d = d + dz * dz;
                float nd = fminf(dd[i], d);
                dd[i] = nd;
                u64 kd = ((u64)__float_as_uint(nd) << 32) | (unsigned)(8191 - (tid + i * 512));
                bk = (kd > bk) ? kd : bk;
            }
#pragma unroll
            for (int off = 1; off < 64; off <<= 1) {
                u64 ok = __shfl_xor(bk, off);
                bk = (ok > bk) ? ok : bk;
            }
            if ((tid & 63) == 0) rkey[par][w] = bk;
            __syncthreads();
            u64 nk = rkey[par][0];
#pragma unroll
            for (int w2 = 1; w2 < 8; ++w2) {
                u64 v2 = rkey[par][w2];
                nk = (v2 > nk) ? v2 : nk;
            }
            int idx = 8191 - (int)(unsigned)(nk & 0xFFFFFFFFull);
            lx = cx[idx]; ly = cy[idx]; lz = cz[idx];
            if (tid == 0) {
                new_xyz[((size_t)b * SPTS + it) * 3 + 0] = lx;
                new_xyz[((size_t)b * SPTS + it) * 3 + 1] = ly;
                new_xyz[((size_t)b * SPTS + it) * 3 + 2] = lz;
            }
        }
    }
}

// ==================== K2: KNN (R9 exact) ====================
__global__ __launch_bounds__(512) void knn_kernel(const float* __restrict__ xyz_s,
                                                  const float* __restrict__ xyz_t,
                                                  const float* __restrict__ new_xyz,
                                                  int* __restrict__ idx_s,
                                                  int* __restrict__ idx_t) {
#pragma clang fp contract(off)
    int q = blockIdx.x;
    int tid = threadIdx.x;
    int w = tid >> 6, lane = tid & 63;
    int set = w >> 2;
    int sw = w & 3;
    int b = q >> 5;

    const float* pts = (set ? xyz_t : xyz_s) + (size_t)b * NPTS * 3;

    float qx = new_xyz[q * 3 + 0];
    float qy = new_xyz[q * 3 + 1];
    float qz = new_xyz[q * 3 + 2];
    float qq = qx * qx + qy * qy;
    qq = qq + qz * qz;

    u64 bd[12];
#pragma unroll
    for (int j = 0; j < 12; ++j) bd[j] = ~0ULL;

    for (int i = 0; i < 2048 / 64; ++i) {
        int p = sw * 2048 + i * 64 + lane;
        float p0 = pts[p * 3 + 0], p1 = pts[p * 3 + 1], p2 = pts[p * 3 + 2];
        float pp = p0 * p0 + p1 * p1; pp = pp + p2 * p2;
        float dot = qx * p0 + qy * p1; dot = dot + qz * p2;
        float d = (qq - 2.0f * dot) + pp;
        unsigned u = __float_as_uint(d);
        u = (u & 0x80000000u) ? ~u : (u | 0x80000000u);
        u64 key = ((u64)u << 32) | (unsigned)p;
        if (key < bd[11]) {
#pragma unroll
            for (int j = 11; j > 0; --j) {
                bool keep = (key >= bd[j]);
                u64 sh = (key >= bd[j - 1]) ? key : bd[j - 1];
                bd[j] = keep ? bd[j] : sh;
            }
            if (key < bd[0]) bd[0] = key;
        }
    }

    __shared__ u64 sd[2][48];

#pragma unroll
    for (int r = 0; r < KNN_K; ++r) {
        u64 cv = bd[0];
#pragma unroll
        for (int off = 1; off < 64; off <<= 1) {
            u64 ov = __shfl_xor(cv, off);
            cv = (ov < cv) ? ov : cv;
        }
        if (lane == 0) sd[set][sw * KNN_K + r] = cv;
        if (cv == bd[0]) {
#pragma unroll
            for (int j = 0; j < 11; ++j) bd[j] = bd[j + 1];
            bd[11] = ~0ULL;
        }
    }
    __syncthreads();

    if (sw == 0) {
        int* outp = (set ? idx_t : idx_s) + q * KNN_K;
        u64 cd = (lane < 48) ? sd[set][lane] : ~0ULL;
#pragma unroll
        for (int r = 0; r < KNN_K; ++r) {
            u64 mv = cd;
#pragma unroll
            for (int off = 1; off < 64; off <<= 1) {
                u64 ov = __shfl_xor(mv, off);
                mv = (ov < mv) ? ov : mv;
            }
            if (lane == 0) outp[r] = (int)(unsigned)(mv & 0xFFFFFFFFull);
            if (cd == mv) cd = ~0ULL;
        }
    }
}

// ==================== K3: barrier-free register-A GEMM ====================
// 1 wave = 1 query (16 rows, 12 valid) x 64 cols. A-frag: lane row = lane&15,
// k window = kgrp*8; 2x float4 f32 load + cvt_pk -> bf16x8. Rows 12-15 read row 0
// (C rows independent; masked in epilogue). B: packed Wb, 4 nf loads = 1KB dense/wave.
template <int KD>
__device__ __forceinline__ void gemm_wave(int q, int ct, const float* __restrict__ feat,
                                          const int* __restrict__ idx,
                                          const ushort_t* __restrict__ Wb,
                                          const float* __restrict__ bias,
                                          const float* __restrict__ gamma,
                                          const float* __restrict__ beta,
                                          const float* __restrict__ mean,
                                          const float* __restrict__ var,
                                          float* __restrict__ out) {
    const int NK = KD / 32;
    int tid = threadIdx.x;
    int w = tid >> 6, lane = tid & 63;
    int lrow = lane & 15, kgrp = lane >> 4;
    int b = q >> 5;

    int rl = (lrow < KNN_K) ? lrow : 0;          // dup row 0 for pad rows
    int src = idx[q * KNN_K + rl];
    const float* ap = feat + ((size_t)b * NPTS + src) * KD + kgrp * 8;
    int colbase = ct * 256 + w * 64;

    f32x4 acc[4];
#pragma unroll
    for (int nf = 0; nf < 4; ++nf) {
        f32x4 z = {0.f, 0.f, 0.f, 0.f};
        acc[nf] = z;
    }

#pragma unroll 4
    for (int kk = 0; kk < NK; ++kk) {
        float4 alo = *reinterpret_cast<const float4*>(ap + kk * 32);
        float4 ahi = *reinterpret_cast<const float4*>(ap + kk * 32 + 4);
        unsigned w0, w1, w2, w3;
        asm("v_cvt_pk_bf16_f32 %0, %1, %2" : "=v"(w0) : "v"(alo.x), "v"(alo.y));
        asm("v_cvt_pk_bf16_f32 %0, %1, %2" : "=v"(w1) : "v"(alo.z), "v"(alo.w));
        asm("v_cvt_pk_bf16_f32 %0, %1, %2" : "=v"(w2) : "v"(ahi.x), "v"(ahi.y));
        asm("v_cvt_pk_bf16_f32 %0, %1, %2" : "=v"(w3) : "v"(ahi.z), "v"(ahi.w));
        union { unsigned u[4]; bf16x8 v; } au;
        au.u[0] = w0; au.u[1] = w1; au.u[2] = w2; au.u[3] = w3;
        bf16x8 af = au.v;

        const ushort_t* bp = Wb + (size_t)kk * (DOUT * 32) + (size_t)(colbase + lrow) * 32 + kgrp * 8;
#pragma unroll
        for (int nf = 0; nf < 4; ++nf) {
            bf16x8 bfr = *reinterpret_cast<const bf16x8*>(bp + nf * 512);
            acc[nf] = __builtin_amdgcn_mfma_f32_16x16x32_bf16(af, bfr, acc[nf], 0, 0, 0);
        }
    }

    // epilogue: BN + ReLU + max over rows 0..11 (rows = kgrp*4+e; kgrp==3 are pads)
#pragma unroll
    for (int nf = 0; nf < 4; ++nf) {
        int col = colbase + nf * 16 + lrow;
        float sc = gamma[col] / sqrtf(var[col] + 1e-5f);
        float sh = (bias[col] - mean[col]) * sc + beta[col];
        float m;
        if (kgrp < 3) {
            float y0 = fmaxf(acc[nf][0] * sc + sh, 0.0f);
            float y1 = fmaxf(acc[nf][1] * sc + sh, 0.0f);
            float y2 = fmaxf(acc[nf][2] * sc + sh, 0.0f);
            float y3 = fmaxf(acc[nf][3] * sc + sh, 0.0f);
            m = fmaxf(fmaxf(y0, y1), fmaxf(y2, y3));
        } else {
            m = -1e30f;
        }
        m = fmaxf(m, __shfl_xor(m, 16));
        m = fmaxf(m, __shfl_xor(m, 32));
        if (kgrp == 0) out[(size_t)q * DOUT + col] = m;
    }
}

struct GP {
    const float* feature_s; const float* feature_t;
    const int* idx_s; const int* idx_t;
    const ushort_t* Wb_s; const ushort_t* Wb_t;
    const float* bias_s; const float* gamma_s; const float* beta_s;
    const float* mean_s; const float* var_s;
    const float* bias_t; const float* gamma_t; const float* beta_t;
    const float* mean_t; const float* var_t;
    float* out;
};

__global__ __launch_bounds__(256, 6) void gemm_kernel(GP P) {
    int bid = blockIdx.x;
    bool is_t = (bid < 2048);              // heavy t tasks dispatch first
    int r2 = bid & 2047;
    int q = r2 >> 2, ct = r2 & 3;
    if (is_t) {
        gemm_wave<DT>(q, ct, P.feature_t, P.idx_t, P.Wb_t, P.bias_t, P.gamma_t,
                      P.beta_t, P.mean_t, P.var_t, P.out + (size_t)512 * 1024);
    } else {
        gemm_wave<DS>(q, ct, P.feature_s, P.idx_s, P.Wb_s, P.bias_s, P.gamma_s,
                      P.beta_s, P.mean_s, P.var_s, P.out);
    }
}

extern "C" void kernel_launch(void* const* d_in, const int* in_sizes, int n_in,
                              void* d_out, int out_size, void* d_ws, size_t ws_size,
                              hipStream_t stream) {
    const float* feature_s = (const float*)d_in[0];
    const float* xyz_s     = (const float*)d_in[1];
    const float* feature_t = (const float*)d_in[2];
    const float* xyz_t     = (const float*)d_in[3];
    const float* Ws        = (const float*)d_in[4];
    const float* Wt        = (const float*)d_in[10];
    float* out = (float*)d_out;

    char* ws = (char*)d_ws;
    float* new_xyz  = (float*)(ws + 0);
    int* idx_s      = (int*)(ws + 8192);
    int* idx_t      = (int*)(ws + 32768);
    ushort_t* Wb_s  = (ushort_t*)(ws + 57344);
    ushort_t* Wb_t  = (ushort_t*)(ws + 581632);

    fps_convw_kernel<<<256, 512, 0, stream>>>(xyz_t, new_xyz, Wt, Wb_t, Ws, Wb_s);
    knn_kernel<<<512, 512, 0, stream>>>(xyz_s, xyz_t, new_xyz, idx_s, idx_t);

    GP P;
    P.feature_s = feature_s; P.feature_t = feature_t;
    P.idx_s = idx_s; P.idx_t = idx_t;
    P.Wb_s = Wb_s; P.Wb_t = Wb_t;
    P.bias_s = (const float*)d_in[5];  P.gamma_s = (const float*)d_in[6];
    P.beta_s = (const float*)d_in[7];  P.mean_s  = (const float*)d_in[8];
    P.var_s  = (const float*)d_in[9];
    P.bias_t = (const float*)d_in[11]; P.gamma_t = (const float*)d_in[12];
    P.beta_t = (const float*)d_in[13]; P.mean_t  = (const float*)d_in[14];
    P.var_t  = (const float*)d_in[15];
    P.out = out;

    gemm_kernel<<<4096, 256, 0, stream>>>(P);
}

// Round 12
// 125.308 us; speedup vs baseline: 17.3526x; 1.6720x over previous
//
#include <hip/hip_runtime.h>
#include <hip/hip_bf16.h>

// RelationCos pipeline in 3 kernels:
//   K1: FPS (blocks 0-15, packed-u64 argmax + LDS coord table) || W->bf16 packed (16-255)
//   K2: KNN (512 blocks, 8 waves; packed-u64) -> idx in ws
//   K3: gather-fused GEMM: block = 2 queries x 512 cols (512 thr, 8 waves), grid 1024
//       -> 4 blocks/CU (thread-capacity cap). LDS 4 slabs [32][44]; 2 barriers / 4 K-steps.
//       Same HBM traffic as the 68us R10 version; 2x the block-level latency overlap.

#define NPTS 8192
#define SPTS 32
#define KNN_K 12
#define DS 256
#define DT 1024
#define DOUT 1024

typedef float f32x4 __attribute__((ext_vector_type(4)));
typedef __bf16 bf16x8 __attribute__((ext_vector_type(8)));
typedef unsigned short ushort_t;
typedef unsigned long long u64;

__device__ __forceinline__ ushort_t f2bf(float f) {
    unsigned int u = __float_as_uint(f);
    u += 0x7fffu + ((u >> 16) & 1u);   // RNE
    return (ushort_t)(u >> 16);
}

// ==================== K1: FPS || W convert (packed) ====================
// Packed layout: element (col,k) -> [k>>5]*(DOUT*32) + col*32 + (k&31)
__global__ __launch_bounds__(512) void fps_convw_kernel(const float* __restrict__ xyz,
                                                        float* __restrict__ new_xyz,
                                                        const float* __restrict__ Wt,
                                                        ushort_t* __restrict__ Wb_t,
                                                        const float* __restrict__ Ws,
                                                        ushort_t* __restrict__ Wb_s) {
    int bid = blockIdx.x;
    int tid = threadIdx.x;

    if (bid >= 16) {
        int lin = (bid - 16) * 512 + tid;
        const int stride = 240 * 512;
        for (int i = lin; i < (DT * DOUT) / 4; i += stride) {   // t: KD=1024
            int col = i >> 8, k4 = i & 255;
            float4 v = reinterpret_cast<const float4*>(Wt)[i];
            ushort4 u;
            u.x = f2bf(v.x); u.y = f2bf(v.y); u.z = f2bf(v.z); u.w = f2bf(v.w);
            size_t off = (size_t)(k4 >> 3) * (DOUT * 32) + col * 32 + (k4 & 7) * 4;
            *reinterpret_cast<ushort4*>(Wb_t + off) = u;
        }
        for (int i = lin; i < (DS * DOUT) / 4; i += stride) {   // s: KD=256
            int col = i >> 6, k4 = i & 63;
            float4 v = reinterpret_cast<const float4*>(Ws)[i];
            ushort4 u;
            u.x = f2bf(v.x); u.y = f2bf(v.y); u.z = f2bf(v.z); u.w = f2bf(v.w);
            size_t off = (size_t)(k4 >> 3) * (DOUT * 32) + col * 32 + (k4 & 7) * 4;
            *reinterpret_cast<ushort4*>(Wb_s + off) = u;
        }
        return;
    }

    {
#pragma clang fp contract(off)
        int b = bid;
        const float* base = xyz + (size_t)b * NPTS * 3;

        __shared__ float cx[NPTS], cy[NPTS], cz[NPTS];   // 96 KB coord table
        __shared__ u64 rkey[2][8];

        float px[16], py[16], pz[16], dd[16];
#pragma unroll
        for (int i = 0; i < 16; ++i) {
            int p = tid + i * 512;
            px[i] = base[p * 3 + 0];
            py[i] = base[p * 3 + 1];
            pz[i] = base[p * 3 + 2];
            dd[i] = 1e10f;
            cx[p] = px[i]; cy[p] = py[i]; cz[p] = pz[i];
        }

        float lx = base[0], ly = base[1], lz = base[2];
        if (tid == 0) {
            new_xyz[((size_t)b * SPTS + 0) * 3 + 0] = lx;
            new_xyz[((size_t)b * SPTS + 0) * 3 + 1] = ly;
            new_xyz[((size_t)b * SPTS + 0) * 3 + 2] = lz;
        }

        int w = tid >> 6;
        for (int it = 1; it < SPTS; ++it) {
            int par = it & 1;
            u64 bk = 0;
#pragma unroll
            for (int i = 0; i < 16; ++i) {
                float dx = px[i] - lx, dy = py[i] - ly, dz = pz[i] - lz;
                float d = dx * dx + dy * dy;
                d = d + dz * dz;
                float nd = fminf(dd[i], d);
                dd[i] = nd;
                u64 kd = ((u64)__float_as_uint(nd) << 32) | (unsigned)(8191 - (tid + i * 512));
                bk = (kd > bk) ? kd : bk;
            }
#pragma unroll
            for (int off = 1; off < 64; off <<= 1) {
                u64 ok = __shfl_xor(bk, off);
                bk = (ok > bk) ? ok : bk;
            }
            if ((tid & 63) == 0) rkey[par][w] = bk;
            __syncthreads();
            u64 nk = rkey[par][0];
#pragma unroll
            for (int w2 = 1; w2 < 8; ++w2) {
                u64 v2 = rkey[par][w2];
                nk = (v2 > nk) ? v2 : nk;
            }
            int idx = 8191 - (int)(unsigned)(nk & 0xFFFFFFFFull);
            lx = cx[idx]; ly = cy[idx]; lz = cz[idx];
            if (tid == 0) {
                new_xyz[((size_t)b * SPTS + it) * 3 + 0] = lx;
                new_xyz[((size_t)b * SPTS + it) * 3 + 1] = ly;
                new_xyz[((size_t)b * SPTS + it) * 3 + 2] = lz;
            }
        }
    }
}

// ==================== K2: KNN (unchanged, passing) ====================
__global__ __launch_bounds__(512) void knn_kernel(const float* __restrict__ xyz_s,
                                                  const float* __restrict__ xyz_t,
                                                  const float* __restrict__ new_xyz,
                                                  int* __restrict__ idx_s,
                                                  int* __restrict__ idx_t) {
#pragma clang fp contract(off)
    int q = blockIdx.x;
    int tid = threadIdx.x;
    int w = tid >> 6, lane = tid & 63;
    int set = w >> 2;
    int sw = w & 3;
    int b = q >> 5;

    const float* pts = (set ? xyz_t : xyz_s) + (size_t)b * NPTS * 3;

    float qx = new_xyz[q * 3 + 0];
    float qy = new_xyz[q * 3 + 1];
    float qz = new_xyz[q * 3 + 2];
    float qq = qx * qx + qy * qy;
    qq = qq + qz * qz;

    u64 bd[12];
#pragma unroll
    for (int j = 0; j < 12; ++j) bd[j] = ~0ULL;

    for (int i = 0; i < 2048 / 64; ++i) {
        int p = sw * 2048 + i * 64 + lane;
        float p0 = pts[p * 3 + 0], p1 = pts[p * 3 + 1], p2 = pts[p * 3 + 2];
        float pp = p0 * p0 + p1 * p1; pp = pp + p2 * p2;
        float dot = qx * p0 + qy * p1; dot = dot + qz * p2;
        float d = (qq - 2.0f * dot) + pp;
        unsigned u = __float_as_uint(d);
        u = (u & 0x80000000u) ? ~u : (u | 0x80000000u);
        u64 key = ((u64)u << 32) | (unsigned)p;
        if (key < bd[11]) {
#pragma unroll
            for (int j = 11; j > 0; --j) {
                bool keep = (key >= bd[j]);
                u64 sh = (key >= bd[j - 1]) ? key : bd[j - 1];
                bd[j] = keep ? bd[j] : sh;
            }
            if (key < bd[0]) bd[0] = key;
        }
    }

    __shared__ u64 sd[2][48];

#pragma unroll
    for (int r = 0; r < KNN_K; ++r) {
        u64 cv = bd[0];
#pragma unroll
        for (int off = 1; off < 64; off <<= 1) {
            u64 ov = __shfl_xor(cv, off);
            cv = (ov < cv) ? ov : cv;
        }
        if (lane == 0) sd[set][sw * KNN_K + r] = cv;
        if (cv == bd[0]) {
#pragma unroll
            for (int j = 0; j < 11; ++j) bd[j] = bd[j + 1];
            bd[11] = ~0ULL;
        }
    }
    __syncthreads();

    if (sw == 0) {
        int* outp = (set ? idx_t : idx_s) + q * KNN_K;
        u64 cd = (lane < 48) ? sd[set][lane] : ~0ULL;
#pragma unroll
        for (int r = 0; r < KNN_K; ++r) {
            u64 mv = cd;
#pragma unroll
            for (int off = 1; off < 64; off <<= 1) {
                u64 ov = __shfl_xor(mv, off);
                mv = (ov < mv) ? ov : mv;
            }
            if (lane == 0) outp[r] = (int)(unsigned)(mv & 0xFFFFFFFFull);
            if (cd == mv) cd = ~0ULL;
        }
    }
}

// ==================== K3: gather-fused GEMM, 2q x 512cols, 4 blocks/CU ====================
// Block: 512 thr / 8 waves; 2 queries (32 rows, 12 valid each) x 512 cols (64/wave).
// LDS: 4 slabs [32][44] bf16 (2-way-free banks). Staging: threads 0-255, float4 each.
// B dense 1KB wave-loads from packed Wb; each B-frag feeds 2 MFMAs (2 m-frags).
template <int KD>
__device__ __forceinline__ void gemm_body(int qg, int ch, const float* __restrict__ feat,
                                          const int* __restrict__ idx,
                                          const ushort_t* __restrict__ Wb,
                                          const float* __restrict__ bias,
                                          const float* __restrict__ gamma,
                                          const float* __restrict__ beta,
                                          const float* __restrict__ mean,
                                          const float* __restrict__ var,
                                          float* __restrict__ out,
                                          ushort_t (*abuf)[32][44]) {
    const int NK = KD / 32;
    int tid = threadIdx.x;
    int w = tid >> 6, lane = tid & 63;
    int lrow = lane & 15, kgrp = lane >> 4;
    int q0 = qg * 2;
    int b = q0 >> 5;                       // q0, q0+1 in same batch (q0 even)

    // staging role (threads 0..255): r = row 0..31 (2 queries x 16), seg = 0..7
    int r = tid >> 3, seg = tid & 7;
    bool stager = (tid < 256);
    int sq = q0 + (r >> 4);
    int sk = r & 15;
    bool valid = stager && (sk < KNN_K);
    int src = valid ? idx[sq * KNN_K + sk] : 0;
    const float* srcp = feat + ((size_t)b * NPTS + src) * KD + seg * 4;

    f32x4 acc[2][4];
#pragma unroll
    for (int mf = 0; mf < 2; ++mf)
#pragma unroll
        for (int nf = 0; nf < 4; ++nf) {
            f32x4 z = {0.f, 0.f, 0.f, 0.f};
            acc[mf][nf] = z;
        }

    // prologue: stage slabs 0..3
    if (stager) {
#pragma unroll
        for (int j = 0; j < 4; ++j) {
            float4 v = {0.f, 0.f, 0.f, 0.f};
            if (valid) v = *reinterpret_cast<const float4*>(srcp + j * 32);
            ushort4 u;
            u.x = f2bf(v.x); u.y = f2bf(v.y); u.z = f2bf(v.z); u.w = f2bf(v.w);
            *reinterpret_cast<ushort4*>(&abuf[j][r][seg * 4]) = u;
        }
    }
    __syncthreads();

    for (int kk = 0; kk < NK; kk += 4) {
        float4 nv0 = {0.f, 0.f, 0.f, 0.f}, nv1 = nv0, nv2 = nv0, nv3 = nv0;
        if (valid && kk + 4 < NK) {
            nv0 = *reinterpret_cast<const float4*>(srcp + (kk + 4) * 32);
            nv1 = *reinterpret_cast<const float4*>(srcp + (kk + 5) * 32);
            nv2 = *reinterpret_cast<const float4*>(srcp + (kk + 6) * 32);
            nv3 = *reinterpret_cast<const float4*>(srcp + (kk + 7) * 32);
        }

#pragma unroll
        for (int ss = 0; ss < 4; ++ss) {
            bf16x8 a0 = *reinterpret_cast<const bf16x8*>(&abuf[ss][lrow][kgrp * 8]);
            bf16x8 a1 = *reinterpret_cast<const bf16x8*>(&abuf[ss][16 + lrow][kgrp * 8]);
#pragma unroll
            for (int nf = 0; nf < 4; ++nf) {
                int col = ch * 512 + w * 64 + nf * 16 + lrow;
                const ushort_t* bp = Wb + (size_t)(kk + ss) * (DOUT * 32) + (size_t)col * 32 + kgrp * 8;
                bf16x8 bfr = *reinterpret_cast<const bf16x8*>(bp);
                acc[0][nf] = __builtin_amdgcn_mfma_f32_16x16x32_bf16(a0, bfr, acc[0][nf], 0, 0, 0);
                acc[1][nf] = __builtin_amdgcn_mfma_f32_16x16x32_bf16(a1, bfr, acc[1][nf], 0, 0, 0);
            }
        }
        __syncthreads();   // all reads of abuf done

        if (kk + 4 < NK) {
            if (stager) {
                ushort4 u0, u1, u2, u3;
                u0.x = f2bf(nv0.x); u0.y = f2bf(nv0.y); u0.z = f2bf(nv0.z); u0.w = f2bf(nv0.w);
                u1.x = f2bf(nv1.x); u1.y = f2bf(nv1.y); u1.z = f2bf(nv1.z); u1.w = f2bf(nv1.w);
                u2.x = f2bf(nv2.x); u2.y = f2bf(nv2.y); u2.z = f2bf(nv2.z); u2.w = f2bf(nv2.w);
                u3.x = f2bf(nv3.x); u3.y = f2bf(nv3.y); u3.z = f2bf(nv3.z); u3.w = f2bf(nv3.w);
                *reinterpret_cast<ushort4*>(&abuf[0][r][seg * 4]) = u0;
                *reinterpret_cast<ushort4*>(&abuf[1][r][seg * 4]) = u1;
                *reinterpret_cast<ushort4*>(&abuf[2][r][seg * 4]) = u2;
                *reinterpret_cast<ushort4*>(&abuf[3][r][seg * 4]) = u3;
            }
            __syncthreads();   // writes visible before next compute
        }
    }

    // epilogue: BN + ReLU + max over rows 0..11 (frag rows = kgrp*4+e; kgrp==3 pads)
#pragma unroll
    for (int nf = 0; nf < 4; ++nf) {
        int col = ch * 512 + w * 64 + nf * 16 + lrow;
        float sc = gamma[col] / sqrtf(var[col] + 1e-5f);
        float sh = (bias[col] - mean[col]) * sc + beta[col];
#pragma unroll
        for (int mf = 0; mf < 2; ++mf) {
            float m;
            if (kgrp < 3) {
                float y0 = fmaxf(acc[mf][nf][0] * sc + sh, 0.0f);
                float y1 = fmaxf(acc[mf][nf][1] * sc + sh, 0.0f);
                float y2 = fmaxf(acc[mf][nf][2] * sc + sh, 0.0f);
                float y3 = fmaxf(acc[mf][nf][3] * sc + sh, 0.0f);
                m = fmaxf(fmaxf(y0, y1), fmaxf(y2, y3));
            } else {
                m = -1e30f;
            }
            m = fmaxf(m, __shfl_xor(m, 16));
            m = fmaxf(m, __shfl_xor(m, 32));
            if (kgrp == 0) out[(size_t)(q0 + mf) * DOUT + col] = m;
        }
    }
}

struct GP {
    const float* feature_s; const float* feature_t;
    const int* idx_s; const int* idx_t;
    const ushort_t* Wb_s; const ushort_t* Wb_t;
    const float* bias_s; const float* gamma_s; const float* beta_s;
    const float* mean_s; const float* var_s;
    const float* bias_t; const float* gamma_t; const float* beta_t;
    const float* mean_t; const float* var_t;
    float* out;
};

__global__ __launch_bounds__(512, 4) void gemm_kernel(GP P) {
    __shared__ ushort_t abuf[4][32][44];   // 11.3 KB
    int bid = blockIdx.x;
    bool is_t = (bid < 512);               // heavy t tasks dispatch first
    int r2 = is_t ? bid : bid - 512;
    int qg = r2 >> 1, ch = r2 & 1;
    if (is_t) {
        gemm_body<DT>(qg, ch, P.feature_t, P.idx_t, P.Wb_t, P.bias_t, P.gamma_t,
                      P.beta_t, P.mean_t, P.var_t, P.out + (size_t)512 * 1024, abuf);
    } else {
        gemm_body<DS>(qg, ch, P.feature_s, P.idx_s, P.Wb_s, P.bias_s, P.gamma_s,
                      P.beta_s, P.mean_s, P.var_s, P.out, abuf);
    }
}

extern "C" void kernel_launch(void* const* d_in, const int* in_sizes, int n_in,
                              void* d_out, int out_size, void* d_ws, size_t ws_size,
                              hipStream_t stream) {
    const float* feature_s = (const float*)d_in[0];
    const float* xyz_s     = (const float*)d_in[1];
    const float* feature_t = (const float*)d_in[2];
    const float* xyz_t     = (const float*)d_in[3];
    const float* Ws        = (const float*)d_in[4];
    const float* Wt        = (const float*)d_in[10];
    float* out = (float*)d_out;

    char* ws = (char*)d_ws;
    float* new_xyz  = (float*)(ws + 0);
    int* idx_s      = (int*)(ws + 8192);
    int* idx_t      = (int*)(ws + 32768);
    ushort_t* Wb_s  = (ushort_t*)(ws + 57344);
    ushort_t* Wb_t  = (ushort_t*)(ws + 581632);

    fps_convw_kernel<<<256, 512, 0, stream>>>(xyz_t, new_xyz, Wt, Wb_t, Ws, Wb_s);
    knn_kernel<<<512, 512, 0, stream>>>(xyz_s, xyz_t, new_xyz, idx_s, idx_t);

    GP P;
    P.feature_s = feature_s; P.feature_t = feature_t;
    P.idx_s = idx_s; P.idx_t = idx_t;
    P.Wb_s = Wb_s; P.Wb_t = Wb_t;
    P.bias_s = (const float*)d_in[5];  P.gamma_s = (const float*)d_in[6];
    P.beta_s = (const float*)d_in[7];  P.mean_s  = (const float*)d_in[8];
    P.var_s  = (const float*)d_in[9];
    P.bias_t = (const float*)d_in[11]; P.gamma_t = (const float*)d_in[12];
    P.beta_t = (const float*)d_in[13]; P.mean_t  = (const float*)d_in[14];
    P.var_t  = (const float*)d_in[15];
    P.out = out;

    gemm_kernel<<<1024, 512, 0, stream>>>(P);
}